// Round 1
// baseline (906.717 us; speedup 1.0000x reference)
//
#include <hip/hip_runtime.h>

typedef unsigned short u16;
typedef unsigned int u32;
typedef __attribute__((ext_vector_type(8))) short short8;   // 8 bf16 = 4 VGPRs
typedef __attribute__((ext_vector_type(4))) float f32x4;

#define NB 8192
#define KTOT 16384
#define JC 256
#define BM 128
#define BK 32
#define SPLITS 8
#define CHUNK 2048          // KTOT / SPLITS
#define KSTEPS 64           // CHUNK / BK

__device__ __forceinline__ u16 f2bf(float f) {
  // round-to-nearest-even fp32 -> bf16
  u32 u = __float_as_uint(f);
  u32 r = (u + 0x7fffu + ((u >> 16) & 1u)) >> 16;
  return (u16)r;
}
__device__ __forceinline__ u32 pack2(float a, float b) {
  return (u32)f2bf(a) | ((u32)f2bf(b) << 16);
}

// ---------------- Kernel 1: Yt[j=b*32+o][k=s*8192+m] = bf16(sum_c x[b,m,c]*W[s,o,c])
__global__ __launch_bounds__(256) void prep_kernel(
    const float* __restrict__ x, const float* __restrict__ W, u16* __restrict__ Yt) {
  __shared__ float Ws[2048];  // 2*32*32
  int tid = threadIdx.x;
  for (int i = tid; i < 2048; i += 256) Ws[i] = W[i];
  __syncthreads();
  int gid = blockIdx.x * 256 + tid;     // (s,b,m), m fastest
  int m = gid & (NB - 1);
  int sb = gid >> 13;
  int b = sb & 7;
  int s = sb >> 3;
  const float4* xp = (const float4*)(x + ((size_t)b * NB + m) * 32);
  float4 xv[8];
#pragma unroll
  for (int i = 0; i < 8; ++i) xv[i] = xp[i];
  u16* yp = Yt + (size_t)(b * 32) * KTOT + (size_t)s * NB + m;
#pragma unroll
  for (int o = 0; o < 32; ++o) {
    const float4* wp = (const float4*)(Ws + (s * 32 + o) * 32);
    float ax = 0.f, ay = 0.f, az = 0.f, aw = 0.f;
#pragma unroll
    for (int i = 0; i < 8; ++i) {
      float4 w = wp[i];
      ax += xv[i].x * w.x; ay += xv[i].y * w.y;
      az += xv[i].z * w.z; aw += xv[i].w * w.w;
    }
    yp[(size_t)o * KTOT] = f2bf((ax + ay) + (az + aw));
  }
}

// ---------------- Kernel 2: split-K GEMM, A fp32 (converted in staging), Yt bf16
template <bool ATOMIC>
__global__ __launch_bounds__(256, 2) void gemm_kernel(
    const float* __restrict__ A, const u16* __restrict__ Yt, float* __restrict__ dst) {
  __shared__ __attribute__((aligned(16))) u16 Alds[BM][40];  // pad 32->40: 16B-aligned rows, 2-way banks
  __shared__ __attribute__((aligned(16))) u16 Blds[JC][40];

  int id = blockIdx.x;
  int ks = id & 7;          // split -> XCD-pinned (id%8 == XCD heuristic): 1MB Y slice stays in one L2
  int rb = id >> 3;         // 0..63 row block
  int n0 = rb * BM;
  int s = ks >> 2;
  int m0 = (ks & 3) * CHUNK;
  const float* Ab = A + (size_t)s * NB * NB + (size_t)n0 * NB + m0;

  int t = threadIdx.x;
  int ar = t >> 1;                 // A staging: row 0..127
  int ah = (t & 1) << 4;           // k-offset 0 or 16
  const float* aptr = Ab + (size_t)ar * NB + ah;
  const u16* bptr = Yt + (size_t)t * KTOT + ks * CHUNK;  // B staging: j-row = t

  int l = t & 63;
  int w = t >> 6;
  int wr = w >> 1, wc = w & 1;     // wave tile 64 rows x 128 cols
  int quad = l >> 4, lr = l & 15;

  f32x4 acc[4][8];
#pragma unroll
  for (int i = 0; i < 4; ++i)
#pragma unroll
    for (int j = 0; j < 8; ++j) acc[i][j] = (f32x4){0.f, 0.f, 0.f, 0.f};

  float4 aReg[4];
  uint4 bReg[4];
  {
    const float4* p = (const float4*)aptr;
    aReg[0] = p[0]; aReg[1] = p[1]; aReg[2] = p[2]; aReg[3] = p[3];
    const uint4* q = (const uint4*)bptr;
    bReg[0] = q[0]; bReg[1] = q[1]; bReg[2] = q[2]; bReg[3] = q[3];
  }

  for (int kt = 0; kt < KSTEPS; ++kt) {
    __syncthreads();   // previous iteration's fragment reads complete
    // stage A (fp32 -> bf16) and B into LDS
    uint4 q0, q1;
    q0.x = pack2(aReg[0].x, aReg[0].y); q0.y = pack2(aReg[0].z, aReg[0].w);
    q0.z = pack2(aReg[1].x, aReg[1].y); q0.w = pack2(aReg[1].z, aReg[1].w);
    q1.x = pack2(aReg[2].x, aReg[2].y); q1.y = pack2(aReg[2].z, aReg[2].w);
    q1.z = pack2(aReg[3].x, aReg[3].y); q1.w = pack2(aReg[3].z, aReg[3].w);
    uint4* adst = (uint4*)&Alds[ar][ah];
    adst[0] = q0; adst[1] = q1;
    uint4* bdst = (uint4*)&Blds[t][0];
    bdst[0] = bReg[0]; bdst[1] = bReg[1]; bdst[2] = bReg[2]; bdst[3] = bReg[3];
    __syncthreads();
    // prefetch next tile into registers: in flight during MFMA phase
    if (kt + 1 < KSTEPS) {
      const float4* p = (const float4*)(aptr + (kt + 1) * BK);
      aReg[0] = p[0]; aReg[1] = p[1]; aReg[2] = p[2]; aReg[3] = p[3];
      const uint4* q = (const uint4*)(bptr + (kt + 1) * BK);
      bReg[0] = q[0]; bReg[1] = q[1]; bReg[2] = q[2]; bReg[3] = q[3];
    }
    short8 af[4], bf[8];
#pragma unroll
    for (int mt = 0; mt < 4; ++mt)
      af[mt] = *(const short8*)&Alds[wr * 64 + mt * 16 + lr][quad * 8];
#pragma unroll
    for (int nt = 0; nt < 8; ++nt)
      bf[nt] = *(const short8*)&Blds[wc * 128 + nt * 16 + lr][quad * 8];
#pragma unroll
    for (int mt = 0; mt < 4; ++mt)
#pragma unroll
      for (int nt = 0; nt < 8; ++nt)
        acc[mt][nt] = __builtin_amdgcn_mfma_f32_16x16x32_bf16(af[mt], bf[nt], acc[mt][nt], 0, 0, 0);
  }

  // epilogue: C/D layout col=lane&15, row=quad*4+reg
#pragma unroll
  for (int mt = 0; mt < 4; ++mt) {
#pragma unroll
    for (int nt = 0; nt < 8; ++nt) {
      int col = wc * 128 + nt * 16 + lr;   // j = b*32+o
#pragma unroll
      for (int r = 0; r < 4; ++r) {
        int row = n0 + wr * 64 + mt * 16 + quad * 4 + r;  // n
        float v = acc[mt][nt][r];
        if (ATOMIC) {
          atomicAdd(&dst[(((size_t)(col >> 5) * NB + row) << 5) + (col & 31)], v);
        } else {
          dst[((size_t)ks << 21) + ((size_t)row << 8) + col] = v;  // P[ks][n][j]
        }
      }
    }
  }
}

// ---------------- Kernel 3: reduce 8 split partials + bias, remap (n,j) -> (b,n,o)
__global__ __launch_bounds__(256) void reduce_kernel(
    const float4* __restrict__ P, const float* __restrict__ bias, float4* __restrict__ out) {
  int gid = blockIdx.x * 256 + threadIdx.x;  // 0..524287 = n*64 + j4
  int j4 = gid & 63;
  int n = gid >> 6;
  float4 s = P[gid];
#pragma unroll
  for (int ks = 1; ks < 8; ++ks) {
    float4 v = P[(ks << 19) + gid];
    s.x += v.x; s.y += v.y; s.z += v.z; s.w += v.w;
  }
  float4 bv = ((const float4*)bias)[j4 & 7];
  s.x += bv.x; s.y += bv.y; s.z += bv.z; s.w += bv.w;
  int b = j4 >> 3;
  out[((size_t)b << 16) + ((size_t)n << 3) + (j4 & 7)] = s;
}

// ---------------- atomic-path init: out[b,n,o] = bias[o]
__global__ __launch_bounds__(256) void init_kernel(float4* __restrict__ out,
                                                   const float* __restrict__ bias) {
  int gid = blockIdx.x * 256 + threadIdx.x;  // 524288 float4s
  out[gid] = ((const float4*)bias)[gid & 7];
}

extern "C" void kernel_launch(void* const* d_in, const int* in_sizes, int n_in,
                              void* d_out, int out_size, void* d_ws, size_t ws_size,
                              hipStream_t stream) {
  const float* x = (const float*)d_in[0];
  const float* supports = (const float*)d_in[1];
  const float* W = (const float*)d_in[2];
  const float* bias = (const float*)d_in[3];
  float* out = (float*)d_out;

  u16* Yt = (u16*)d_ws;                                  // 8 MB
  const size_t Y_BYTES = (size_t)8 << 20;
  const size_t P_BYTES = (size_t)64 << 20;

  prep_kernel<<<512, 256, 0, stream>>>(x, W, Yt);

  if (ws_size >= Y_BYTES + P_BYTES) {
    float* P = (float*)((char*)d_ws + Y_BYTES);          // 64 MB partials
    gemm_kernel<false><<<512, 256, 0, stream>>>(supports, Yt, P);
    reduce_kernel<<<2048, 256, 0, stream>>>((const float4*)P, bias, (float4*)out);
  } else {
    init_kernel<<<2048, 256, 0, stream>>>((float4*)out, bias);
    gemm_kernel<true><<<512, 256, 0, stream>>>(supports, Yt, out);
  }
}